// Round 1
// baseline (48.779 us; speedup 1.0000x reference)
//
#include <hip/hip_runtime.h>
#include <math.h>

#define NB   64
#define CCH  512
#define SZ   28
#define HW   784          // 28*28
#define NCHUNK 8
#define CPC  (CCH / NCHUNK)   // 64 channels per chunk
#define Q4   (HW / 4)         // 196 float4 per row

// output layout (floats):
//   [0, 100352)          relative_coord_total  [64,784,2]
//   [100352, 100480)     basic_anchor          [64,2]
//   [100480, ...)        position_weight       [64,784,784]
#define OFF_ANCHOR 100352
#define OFF_PW     100480

// ---------------- K1: partial channel sums ----------------
// grid (NCHUNK, NB), block 256. Each block sums 64 channels for one sample.
__global__ __launch_bounds__(256) void k_partial(const float* __restrict__ x,
                                                 float* __restrict__ partial) {
    const int chunk = blockIdx.x;
    const int n     = blockIdx.y;
    const int t     = threadIdx.x;
    if (t >= Q4) return;

    const float* xp = x + (size_t)n * CCH * HW + (size_t)chunk * CPC * HW + 4 * t;
    float4 acc = make_float4(0.f, 0.f, 0.f, 0.f);
    #pragma unroll 4
    for (int c = 0; c < CPC; ++c) {
        float4 v = *(const float4*)(xp + (size_t)c * HW);
        acc.x += v.x; acc.y += v.y; acc.z += v.z; acc.w += v.w;
    }
    *(float4*)(partial + ((size_t)n * NCHUNK + chunk) * HW + 4 * t) = acc;
}

// ---------------- K2: threshold, argmax, anchor, coords, pw ----------------
// grid NB, block 256.
__global__ __launch_bounds__(256) void k_reduce(const float* __restrict__ partial,
                                                float* __restrict__ out,
                                                float* __restrict__ pw) {
    const int n = blockIdx.x;
    const int t = threadIdx.x;

    __shared__ float mask[HW];
    __shared__ float red[256];
    __shared__ int   redi[256];

    float local = 0.f;
    if (t < Q4) {
        float4 acc = make_float4(0.f, 0.f, 0.f, 0.f);
        #pragma unroll
        for (int ch = 0; ch < NCHUNK; ++ch) {
            float4 v = *(const float4*)(partial + ((size_t)n * NCHUNK + ch) * HW + 4 * t);
            acc.x += v.x; acc.y += v.y; acc.z += v.z; acc.w += v.w;
        }
        *(float4*)(mask + 4 * t) = acc;
        local = acc.x + acc.y + acc.z + acc.w;
    }

    // block reduce -> threshold (mean of mask)
    red[t] = local;
    __syncthreads();
    for (int s = 128; s > 0; s >>= 1) {
        if (t < s) red[t] += red[t + s];
        __syncthreads();
    }
    const float thr = red[0] * (1.0f / HW);
    __syncthreads();   // protect red[] reuse below

    // scores = (mask > thr) ? mask/C : 0 ; first-occurrence argmax
    float bv = -INFINITY; int bp = HW;
    for (int p = t; p < HW; p += 256) {
        float m = mask[p];
        float s = (m > thr) ? m * (1.0f / CCH) : 0.0f;
        if (s > bv) { bv = s; bp = p; }     // ascending p -> first within thread
    }
    red[t] = bv; redi[t] = bp;
    __syncthreads();
    for (int s = 128; s > 0; s >>= 1) {
        if (t < s) {
            float ov = red[t + s]; int op = redi[t + s];
            if (ov > red[t] || (ov == red[t] && op < redi[t])) { red[t] = ov; redi[t] = op; }
        }
        __syncthreads();
    }
    const int   idx = redi[0];
    const float ai  = (float)(idx / SZ);
    const float aj  = (float)(idx % SZ);

    if (t == 0) {
        out[OFF_ANCHOR + n * 2 + 0] = ai;
        out[OFF_ANCHOR + n * 2 + 1] = aj;
    }

    const float inv_sz = 1.0f / (float)SZ;
    const float inv_pi = 0.31830988618367444f;   // 1/pi
    for (int p = t; p < HW; p += 256) {
        float ci = ((float)(p / SZ) - ai) * inv_sz;
        float cj = ((float)(p % SZ) - aj) * inv_sz;
        float dist = sqrtf(ci * ci + cj * cj);
        float ang  = (atan2f(cj, ci) * inv_pi + 1.0f) * 0.5f;
        ((float2*)out)[(size_t)n * HW + p] = make_float2(dist, ang);
        pw[n * HW + p] = mask[p] * (1.0f / CCH);
    }
}

// ---------------- K3: rank-1 outer product ----------------
// grid (98, NB), block 256; 8 rows per block.
#define ROWS 8
__global__ __launch_bounds__(256) void k_outer(const float* __restrict__ pw,
                                               float* __restrict__ out) {
    const int tile = blockIdx.x;   // 0..97
    const int n    = blockIdx.y;
    const int t    = threadIdx.x;

    __shared__ float row[HW];
    if (t < Q4) ((float4*)row)[t] = ((const float4*)(pw + (size_t)n * HW))[t];
    __syncthreads();

    if (t >= Q4) return;
    float4 v = ((float4*)row)[t];
    float* obase = out + OFF_PW + ((size_t)n * HW + (size_t)tile * ROWS) * HW;
    #pragma unroll
    for (int r = 0; r < ROWS; ++r) {
        float a = row[tile * ROWS + r];
        float4 w = make_float4(a * v.x, a * v.y, a * v.z, a * v.w);
        ((float4*)(obase + (size_t)r * HW))[t] = w;
    }
}

extern "C" void kernel_launch(void* const* d_in, const int* in_sizes, int n_in,
                              void* d_out, int out_size, void* d_ws, size_t ws_size,
                              hipStream_t stream) {
    const float* x = (const float*)d_in[0];
    float* out = (float*)d_out;

    // workspace: partials [NB*NCHUNK*HW] then pw [NB*HW]  (~1.76 MB total)
    float* partial = (float*)d_ws;
    float* pw      = partial + (size_t)NB * NCHUNK * HW;

    k_partial<<<dim3(NCHUNK, NB), 256, 0, stream>>>(x, partial);
    k_reduce <<<dim3(NB),        256, 0, stream>>>(partial, out, pw);
    k_outer  <<<dim3(98, NB),    256, 0, stream>>>(pw, out);
}